// Round 1
// baseline (5455.611 us; speedup 1.0000x reference)
//
#include <hip/hip_runtime.h>
#include <hip/hip_bf16.h>

#define B_    2
#define C_    256
#define HW_   56
#define N_    3136     // 56*56
#define NH_   8
#define D_    32
#define K1CNT 1568     // N_/2
#define K2CNT 1045     // N_//3
#define LN_EPS 1e-5f
#define SROW  3140     // padded score row (3140 % 32 == 4 -> conflict-free r-strided reads)
#define TJ    128      // AV j-tile

// ---------------- helpers ----------------
__device__ inline unsigned ordf(float f) {
    unsigned u = __float_as_uint(f);
    return u ^ (((unsigned)((int)u >> 31)) | 0x80000000u);
}

// ---------------- pooling (3 avg pools summed, zero-pad, divisor k*k) -------
__global__ void pool_kernel(const float* __restrict__ y, float* __restrict__ yp)
{
    int gid = blockIdx.x * 256 + threadIdx.x;      // b*C*N + c*N + n (n fastest)
    int n  = gid % N_;
    int bc = gid / N_;
    const float* src = y + (size_t)bc * N_;
    int x0 = n % HW_, y0 = n / HW_;
    float acc = 0.f;
#pragma unroll
    for (int dy = -3; dy <= 3; ++dy) {
        int yy = y0 + dy;
        if ((unsigned)yy >= HW_) continue;
#pragma unroll
        for (int dx = -3; dx <= 3; ++dx) {
            int xx = x0 + dx;
            if ((unsigned)xx >= HW_) continue;
            float w = 1.f / 49.f;
            if (dy >= -2 && dy <= 2 && dx >= -2 && dx <= 2) w += 1.f / 25.f;
            if (dy >= -1 && dy <= 1 && dx >= -1 && dx <= 1) w += 1.f / 9.f;
            acc += w * src[yy * HW_ + xx];
        }
    }
    yp[gid] = acc;
}

// ---------------- layernorm over C, writes transposed [B,C,N] ---------------
__global__ void ln_kernel(const float* __restrict__ yp, const float* __restrict__ lnw,
                          const float* __restrict__ lnb, float* __restrict__ yfT)
{
    __shared__ float wr[8];
    __shared__ float stats[2];
    int idx = blockIdx.x;            // b*N + n
    int b = idx / N_, n = idx % N_;
    int c = threadIdx.x;
    size_t off = ((size_t)b * C_ + c) * N_ + n;
    float v = yp[off];
    float s = v, q = v * v;
    int lane = threadIdx.x & 63, wid = threadIdx.x >> 6;
#pragma unroll
    for (int d = 32; d; d >>= 1) { s += __shfl_down(s, d, 64); q += __shfl_down(q, d, 64); }
    if (lane == 0) { wr[wid] = s; wr[4 + wid] = q; }
    __syncthreads();
    if (threadIdx.x == 0) {
        float ts = wr[0] + wr[1] + wr[2] + wr[3];
        float tq = wr[4] + wr[5] + wr[6] + wr[7];
        float mu = ts * (1.f / C_);
        float var = tq * (1.f / C_) - mu * mu;
        stats[0] = mu; stats[1] = rsqrtf(var + LN_EPS);
    }
    __syncthreads();
    yfT[off] = (v - stats[0]) * stats[1] * lnw[c] + lnb[c];
}

// ---------------- GEMM: out = A(AT layout [B,C,N]) @ W[O,K]^T + bias --------
// MODE "qkv": stores d-contiguous into [B,NH,N,D] dest(s) (split at o=256 for kv)
__global__ __launch_bounds__(256) void gemm_qkv(
    const float* __restrict__ A, const float* __restrict__ W,
    const float* __restrict__ bias, float* __restrict__ dst0,
    float* __restrict__ dst1, float scale)
{
    __shared__ float As[16][64];
    __shared__ float Ws[16][68];
    int tid = threadIdx.x;
    int m0 = blockIdx.x * 64;
    int b = m0 / N_, n0 = m0 % N_;
    int o0 = blockIdx.y * 64;
    const float* Ab = A + (size_t)b * C_ * N_;
    float acc[4][4] = {};
    int la_k = tid >> 4;
    int la_m = (tid & 15) * 4;
    int lw_o = tid >> 2;
    int lw_k = (tid & 3) * 4;
    int u  = tid & 15;     // o-group (4 contiguous o)
    int v_ = tid >> 4;     // m lane (stride-16 m frag)
    for (int kt = 0; kt < 16; ++kt) {
        int k0 = kt * 16;
        float4 av = *(const float4*)&Ab[(size_t)(k0 + la_k) * N_ + n0 + la_m];
        float4 wv = *(const float4*)&W[(size_t)(o0 + lw_o) * C_ + k0 + lw_k];
        __syncthreads();
        *(float4*)&As[la_k][la_m] = av;
        Ws[lw_k + 0][lw_o] = wv.x; Ws[lw_k + 1][lw_o] = wv.y;
        Ws[lw_k + 2][lw_o] = wv.z; Ws[lw_k + 3][lw_o] = wv.w;
        __syncthreads();
#pragma unroll
        for (int k = 0; k < 16; ++k) {
            float4 wf = *(const float4*)&Ws[k][u * 4];
            float a0 = As[k][v_], a1 = As[k][v_ + 16], a2 = As[k][v_ + 32], a3 = As[k][v_ + 48];
            acc[0][0] += wf.x * a0; acc[0][1] += wf.x * a1; acc[0][2] += wf.x * a2; acc[0][3] += wf.x * a3;
            acc[1][0] += wf.y * a0; acc[1][1] += wf.y * a1; acc[1][2] += wf.y * a2; acc[1][3] += wf.y * a3;
            acc[2][0] += wf.z * a0; acc[2][1] += wf.z * a1; acc[2][2] += wf.z * a2; acc[2][3] += wf.z * a3;
            acc[3][0] += wf.w * a0; acc[3][1] += wf.w * a1; acc[3][2] += wf.w * a2; acc[3][3] += wf.w * a3;
        }
    }
    int oc = o0 + u * 4;
    float b0v = bias[oc], b1v = bias[oc + 1], b2v = bias[oc + 2], b3v = bias[oc + 3];
    float* dst = dst0; int c2 = oc;
    if (dst1 && oc >= C_) { dst = dst1; c2 = oc - C_; }
    int h = c2 >> 5, d0 = c2 & 31;
    size_t base = ((size_t)b * NH_ + h) * N_ * D_;
#pragma unroll
    for (int j = 0; j < 4; ++j) {
        int n = n0 + v_ + j * 16;
        float4 val;
        val.x = (acc[0][j] + b0v) * scale;
        val.y = (acc[1][j] + b1v) * scale;
        val.z = (acc[2][j] + b2v) * scale;
        val.w = (acc[3][j] + b3v) * scale;
        *(float4*)&dst[base + (size_t)n * D_ + d0] = val;
    }
}

// MODE "proj": stores o-major [B,O,N] (the final output layout), n-contiguous
__global__ __launch_bounds__(256) void gemm_proj(
    const float* __restrict__ A, const float* __restrict__ W,
    const float* __restrict__ bias, float* __restrict__ out)
{
    __shared__ float As[16][64];
    __shared__ float Ws[16][68];
    int tid = threadIdx.x;
    int m0 = blockIdx.x * 64;
    int b = m0 / N_, n0 = m0 % N_;
    int o0 = blockIdx.y * 64;
    const float* Ab = A + (size_t)b * C_ * N_;
    float acc[4][4] = {};
    int la_k = tid >> 4;
    int la_m = (tid & 15) * 4;
    int lw_o = tid >> 2;
    int lw_k = (tid & 3) * 4;
    int u  = tid & 15;     // m-group (4 contiguous m)
    int v_ = tid >> 4;     // o lane (stride-16 o frag)
    for (int kt = 0; kt < 16; ++kt) {
        int k0 = kt * 16;
        float4 av = *(const float4*)&Ab[(size_t)(k0 + la_k) * N_ + n0 + la_m];
        float4 wv = *(const float4*)&W[(size_t)(o0 + lw_o) * C_ + k0 + lw_k];
        __syncthreads();
        *(float4*)&As[la_k][la_m] = av;
        Ws[lw_k + 0][lw_o] = wv.x; Ws[lw_k + 1][lw_o] = wv.y;
        Ws[lw_k + 2][lw_o] = wv.z; Ws[lw_k + 3][lw_o] = wv.w;
        __syncthreads();
#pragma unroll
        for (int k = 0; k < 16; ++k) {
            float4 af = *(const float4*)&As[k][u * 4];
            float w0 = Ws[k][v_], w1 = Ws[k][v_ + 16], w2 = Ws[k][v_ + 32], w3 = Ws[k][v_ + 48];
            acc[0][0] += w0 * af.x; acc[0][1] += w0 * af.y; acc[0][2] += w0 * af.z; acc[0][3] += w0 * af.w;
            acc[1][0] += w1 * af.x; acc[1][1] += w1 * af.y; acc[1][2] += w1 * af.z; acc[1][3] += w1 * af.w;
            acc[2][0] += w2 * af.x; acc[2][1] += w2 * af.y; acc[2][2] += w2 * af.z; acc[2][3] += w2 * af.w;
            acc[3][0] += w3 * af.x; acc[3][1] += w3 * af.y; acc[3][2] += w3 * af.z; acc[3][3] += w3 * af.w;
        }
    }
#pragma unroll
    for (int i = 0; i < 4; ++i) {
        int o = o0 + v_ + i * 16;
        float bb = bias[o];
        float4 val;
        val.x = acc[i][0] + bb; val.y = acc[i][1] + bb;
        val.z = acc[i][2] + bb; val.w = acc[i][3] + bb;
        *(float4*)&out[((size_t)b * C_ + o) * N_ + n0 + u * 4] = val;
    }
}

// ---------------- fused attention ----------------
struct AttnMisc {
    float rowmax[8];
    unsigned thrU[16];
    float coef[16];
    float pp[2];
    int wtot[4];
    float wred[8];
    int selb[4];
    int selr[4];
};

__device__ inline void histSearch(unsigned* hist, AttnMisc* M, int tid, int k, int slot)
{
    int lane = tid & 63, wid = tid >> 6;
    int b0 = tid * 16;
    int h[16], ls[16];
#pragma unroll
    for (int i = 0; i < 16; ++i) h[i] = (int)hist[b0 + i];
    ls[15] = h[15];
#pragma unroll
    for (int i = 14; i >= 0; --i) ls[i] = ls[i + 1] + h[i];
    int tt = ls[0];
    int s = tt;
#pragma unroll
    for (int d = 1; d < 64; d <<= 1) {
        int o = __shfl_down(s, d, 64);
        if (lane + d < 64) s += o;
    }
    if (lane == 0) M->wtot[wid] = s;
    __syncthreads();
    int off = 0;
    for (int w2 = wid + 1; w2 < 4; ++w2) off += M->wtot[w2];
    int after = off + (s - tt);
#pragma unroll
    for (int i = 0; i < 16; ++i) {
        int G = ls[i] + after;                 // count of keys in bins >= b0+i
        if (G >= k && G - h[i] < k) { M->selb[slot] = b0 + i; M->selr[slot] = k - (G - h[i]); }
    }
    __syncthreads();
}

__global__ __launch_bounds__(256) void attn_kernel(
    const float* __restrict__ qh, const float* __restrict__ kh, const float* __restrict__ vh,
    const float* __restrict__ p1p, const float* __restrict__ p2p,
    float* __restrict__ aoT)
{
    extern __shared__ char smem[];
    float*    S    = (float*)smem;                    // 8*3140 fp32      (100480 B)
    float*    qs   = (float*)(smem + 100480);         // 256 fp32         (1024 B)
    unsigned* hist = (unsigned*)(smem + 101504);      // 4096 u32         (16384 B)
    float*    vt   = (float*)(smem + 117888);         // 128*32 fp32      (16384 B)
    float*    red  = (float*)(smem + 134272);         // 4*64*4 fp32      (4096 B)
    AttnMisc* M    = (AttnMisc*)(smem + 138368);

    int tid = threadIdx.x;
    int lane = tid & 63, wid = tid >> 6;
    int bh = blockIdx.y;
    int n0 = blockIdx.x * 8;
    size_t bhN = (size_t)bh * N_;

    if (tid == 0) { M->pp[0] = p1p[0]; M->pp[1] = p2p[0]; }
    qs[tid] = qh[(bhN + n0) * D_ + tid];
    __syncthreads();

    // ---- scores: S[r][j] = q[n0+r] . k[j]  (q pre-scaled by 1/sqrt(d)) ----
    float lmax[8];
#pragma unroll
    for (int r = 0; r < 8; ++r) lmax[r] = -3.4e38f;
    for (int i = 0; i < 13; ++i) {
        int j = tid + (i << 8);
        if (j < N_) {
            const float4* kp = (const float4*)(kh + (bhN + j) * D_);
            float4 k4[8];
#pragma unroll
            for (int q = 0; q < 8; ++q) k4[q] = kp[q];
#pragma unroll
            for (int r = 0; r < 8; ++r) {
                float sacc = 0.f;
#pragma unroll
                for (int q = 0; q < 8; ++q) {
                    float4 q4 = *(const float4*)&qs[r * D_ + q * 4];
                    sacc += q4.x * k4[q].x + q4.y * k4[q].y + q4.z * k4[q].z + q4.w * k4[q].w;
                }
                S[r * SROW + j] = sacc;
                lmax[r] = fmaxf(lmax[r], sacc);
            }
        }
    }
    __syncthreads();

    // ---- row max ----
    for (int r = 0; r < 8; ++r) {
        float v = lmax[r];
#pragma unroll
        for (int d = 32; d; d >>= 1) v = fmaxf(v, __shfl_down(v, d, 64));
        if (lane == 0) M->wred[wid] = v;
        __syncthreads();
        if (tid == 0)
            M->rowmax[r] = fmaxf(fmaxf(M->wred[0], M->wred[1]), fmaxf(M->wred[2], M->wred[3]));
        __syncthreads();
    }

    // ---- exact k-th largest per row via 3-level radix histogram ----
    for (int r = 0; r < 8; ++r) {
        float* Sr = S + r * SROW;
        for (int i = tid; i < 4096; i += 256) hist[i] = 0;
        __syncthreads();
        for (int i = 0; i < 13; ++i) {
            int j = tid + (i << 8);
            if (j < N_) atomicAdd(&hist[ordf(Sr[j]) >> 20], 1u);
        }
        __syncthreads();
        histSearch(hist, M, tid, K1CNT, 0);
        histSearch(hist, M, tid, K2CNT, 1);
        for (int kk = 0; kk < 2; ++kk) {
            unsigned b1 = (unsigned)M->selb[kk];
            int rem1 = M->selr[kk];
            // level 2 (bits 19:8)
            for (int i = tid; i < 4096; i += 256) hist[i] = 0;
            __syncthreads();
            for (int i = 0; i < 13; ++i) {
                int j = tid + (i << 8);
                if (j < N_) {
                    unsigned u2 = ordf(Sr[j]);
                    if ((u2 >> 20) == b1) atomicAdd(&hist[(u2 >> 8) & 0xFFFu], 1u);
                }
            }
            __syncthreads();
            histSearch(hist, M, tid, rem1, 2);
            unsigned b2 = (unsigned)M->selb[2];
            int rem2 = M->selr[2];
            // level 3 (bits 7:0)
            for (int i = tid; i < 4096; i += 256) hist[i] = 0;
            __syncthreads();
            unsigned pref = (b1 << 12) | b2;
            for (int i = 0; i < 13; ++i) {
                int j = tid + (i << 8);
                if (j < N_) {
                    unsigned u3 = ordf(Sr[j]);
                    if ((u3 >> 8) == pref) atomicAdd(&hist[u3 & 0xFFu], 1u);
                }
            }
            __syncthreads();
            histSearch(hist, M, tid, rem2, 3);
            if (tid == 0) M->thrU[r * 2 + kk] = (b1 << 20) | (b2 << 8) | (unsigned)M->selb[3];
            __syncthreads();
        }
    }

    // ---- masked sums + signed markers (w: in both sets, -w: set1 only) ----
    float p1 = M->pp[0], p2 = M->pp[1];
    for (int r = 0; r < 8; ++r) {
        float* Sr = S + r * SROW;
        unsigned t1 = M->thrU[r * 2], t2 = M->thrU[r * 2 + 1];
        float m = M->rowmax[r];
        float ls1 = 0.f, ls2 = 0.f;
        for (int i = 0; i < 13; ++i) {
            int j = tid + (i << 8);
            if (j < N_) {
                float a = Sr[j];
                unsigned u = ordf(a);
                float outv = 0.f;
                if (u >= t1) {
                    float w = __expf(a - m);
                    ls1 += w;
                    if (u >= t2) { ls2 += w; outv = w; }
                    else outv = -w;
                }
                Sr[j] = outv;
            }
        }
#pragma unroll
        for (int d = 32; d; d >>= 1) { ls1 += __shfl_down(ls1, d, 64); ls2 += __shfl_down(ls2, d, 64); }
        if (lane == 0) { M->wred[wid] = ls1; M->wred[4 + wid] = ls2; }
        __syncthreads();
        if (tid == 0) {
            float s1 = M->wred[0] + M->wred[1] + M->wred[2] + M->wred[3];
            float s2 = M->wred[4] + M->wred[5] + M->wred[6] + M->wred[7];
            M->coef[r * 2] = p1 / s1;
            M->coef[r * 2 + 1] = p2 / s2;
        }
        __syncthreads();
    }

    // ---- markers -> combined coefficients ----
    for (int r = 0; r < 8; ++r) {
        float c1 = M->coef[r * 2], c12 = M->coef[r * 2] + M->coef[r * 2 + 1];
        float* Sr = S + r * SROW;
        for (int i = 0; i < 13; ++i) {
            int j = tid + (i << 8);
            if (j < N_) {
                float v = Sr[j];
                Sr[j] = (v > 0.f) ? v * c12 : ((v < 0.f) ? (-v) * c1 : 0.f);
            }
        }
    }
    __syncthreads();

    // ---- AV: out[r][d] = sum_j coeff[r][j] * V[j][d] ----
    int r_ = lane >> 3, dq = lane & 7;
    float acc0 = 0, acc1 = 0, acc2 = 0, acc3 = 0;
    for (int j0 = 0; j0 < N_; j0 += TJ) {
        int cnt = min(TJ, N_ - j0);
        __syncthreads();
        int nf4 = cnt * 8;
        for (int f = tid; f < nf4; f += 256)
            *(float4*)&vt[f * 4] = *(const float4*)&vh[(bhN + j0) * D_ + f * 4];
        __syncthreads();
        int jl0 = wid * 32;
        int lim = min(32, cnt - jl0);
        for (int jj = 0; jj < lim; ++jj) {
            int jl = jl0 + jj;
            float c = S[r_ * SROW + j0 + jl];
            float4 v4 = *(const float4*)&vt[jl * D_ + dq * 4];
            acc0 += c * v4.x; acc1 += c * v4.y; acc2 += c * v4.z; acc3 += c * v4.w;
        }
    }
    float* myred = red + (wid * 64 + lane) * 4;
    myred[0] = acc0; myred[1] = acc1; myred[2] = acc2; myred[3] = acc3;
    __syncthreads();
    if (wid == 0) {
#pragma unroll
        for (int w2 = 1; w2 < 4; ++w2) {
            const float* rr = red + (w2 * 64 + lane) * 4;
            acc0 += rr[0]; acc1 += rr[1]; acc2 += rr[2]; acc3 += rr[3];
        }
        int b = bh >> 3, h = bh & 7;
        int c0 = h * D_ + dq * 4;
        int n = n0 + r_;
        size_t ob = ((size_t)b * C_ + c0) * N_ + n;
        aoT[ob] = acc0;
        aoT[ob + N_] = acc1;
        aoT[ob + (size_t)2 * N_] = acc2;
        aoT[ob + (size_t)3 * N_] = acc3;
    }
}

static const int ATTN_SMEM = 138368 + (int)sizeof(AttnMisc);

extern "C" void kernel_launch(void* const* d_in, const int* in_sizes, int n_in,
                              void* d_out, int out_size, void* d_ws, size_t ws_size,
                              hipStream_t stream)
{
    (void)in_sizes; (void)n_in; (void)out_size; (void)ws_size;
    const float* x    = (const float*)d_in[0];
    const float* y    = (const float*)d_in[1];
    const float* q_w  = (const float*)d_in[2];
    const float* q_b  = (const float*)d_in[3];
    const float* kv_w = (const float*)d_in[4];
    const float* kv_b = (const float*)d_in[5];
    const float* p_w  = (const float*)d_in[6];
    const float* p_b  = (const float*)d_in[7];
    const float* lnw  = (const float*)d_in[8];
    const float* lnb  = (const float*)d_in[9];
    const float* a1p  = (const float*)d_in[10];
    const float* a2p  = (const float*)d_in[11];
    float* out = (float*)d_out;

    float* ws = (float*)d_ws;
    const size_t PLANE = (size_t)B_ * C_ * N_;   // 1,605,632 floats
    float* yp  = ws;
    float* yfT = ws + PLANE;
    float* qh_ = ws + 2 * PLANE;
    float* kh_ = ws + 3 * PLANE;
    float* vh_ = ws + 4 * PLANE;
    float* aoT = ws + 5 * PLANE;

    pool_kernel<<<dim3((unsigned)(PLANE / 256)), 256, 0, stream>>>(y, yp);
    ln_kernel<<<dim3(B_ * N_), 256, 0, stream>>>(yp, lnw, lnb, yfT);
    // q = (x^T @ q_w^T + q_b) * 1/sqrt(32), stored [B,NH,N,D]
    gemm_qkv<<<dim3(98, 4), 256, 0, stream>>>(x, q_w, q_b, qh_, nullptr, 0.17677669529663687f);
    // kv = yf @ kv_w^T + kv_b -> k,v stored [B,NH,N,D]
    gemm_qkv<<<dim3(98, 8), 256, 0, stream>>>(yfT, kv_w, kv_b, kh_, vh_, 1.0f);
    hipFuncSetAttribute(reinterpret_cast<const void*>(attn_kernel),
                        hipFuncAttributeMaxDynamicSharedMemorySize, ATTN_SMEM);
    attn_kernel<<<dim3(N_ / 8, B_ * NH_), 256, ATTN_SMEM, stream>>>(qh_, kh_, vh_, a1p, a2p, aoT);
    gemm_proj<<<dim3(98, 4), 256, 0, stream>>>(aoT, p_w, p_b, out);
}

// Round 2
// 1684.530 us; speedup vs baseline: 3.2387x; 3.2387x over previous
//
#include <hip/hip_runtime.h>
#include <hip/hip_bf16.h>

#define B_    2
#define C_    256
#define HW_   56
#define N_    3136     // 56*56
#define NH_   8
#define D_    32
#define K1CNT 1568     // N_/2
#define K2CNT 1045     // N_//3
#define LN_EPS 1e-5f
#define SROW  3140     // padded score row; 3140%32==4 -> r-strided reads hit distinct banks
#define TJ    128      // AV j-tile
#define HSTR  260      // histogram row stride; 260%32==4 -> rows spread across banks

// ---------------- helpers ----------------
__device__ inline unsigned ordf(float f) {
    unsigned u = __float_as_uint(f);
    return u ^ (((unsigned)((int)u >> 31)) | 0x80000000u);
}

// ---------------- pooling (3 avg pools summed, zero-pad, divisor k*k) -------
__global__ void pool_kernel(const float* __restrict__ y, float* __restrict__ yp)
{
    int gid = blockIdx.x * 256 + threadIdx.x;      // b*C*N + c*N + n (n fastest)
    int n  = gid % N_;
    int bc = gid / N_;
    const float* src = y + (size_t)bc * N_;
    int x0 = n % HW_, y0 = n / HW_;
    float acc = 0.f;
#pragma unroll
    for (int dy = -3; dy <= 3; ++dy) {
        int yy = y0 + dy;
        if ((unsigned)yy >= HW_) continue;
#pragma unroll
        for (int dx = -3; dx <= 3; ++dx) {
            int xx = x0 + dx;
            if ((unsigned)xx >= HW_) continue;
            float w = 1.f / 49.f;
            if (dy >= -2 && dy <= 2 && dx >= -2 && dx <= 2) w += 1.f / 25.f;
            if (dy >= -1 && dy <= 1 && dx >= -1 && dx <= 1) w += 1.f / 9.f;
            acc += w * src[yy * HW_ + xx];
        }
    }
    yp[gid] = acc;
}

// ---------------- layernorm over C, writes transposed [B,C,N] ---------------
__global__ void ln_kernel(const float* __restrict__ yp, const float* __restrict__ lnw,
                          const float* __restrict__ lnb, float* __restrict__ yfT)
{
    __shared__ float wr[8];
    __shared__ float stats[2];
    int idx = blockIdx.x;            // b*N + n
    int b = idx / N_, n = idx % N_;
    int c = threadIdx.x;
    size_t off = ((size_t)b * C_ + c) * N_ + n;
    float v = yp[off];
    float s = v, q = v * v;
    int lane = threadIdx.x & 63, wid = threadIdx.x >> 6;
#pragma unroll
    for (int d = 32; d; d >>= 1) { s += __shfl_down(s, d, 64); q += __shfl_down(q, d, 64); }
    if (lane == 0) { wr[wid] = s; wr[4 + wid] = q; }
    __syncthreads();
    if (threadIdx.x == 0) {
        float ts = wr[0] + wr[1] + wr[2] + wr[3];
        float tq = wr[4] + wr[5] + wr[6] + wr[7];
        float mu = ts * (1.f / C_);
        float var = tq * (1.f / C_) - mu * mu;
        stats[0] = mu; stats[1] = rsqrtf(var + LN_EPS);
    }
    __syncthreads();
    yfT[off] = (v - stats[0]) * stats[1] * lnw[c] + lnb[c];
}

// ---------------- GEMM: out = A(AT layout [B,C,N]) @ W[O,K]^T + bias --------
__global__ __launch_bounds__(256) void gemm_qkv(
    const float* __restrict__ A, const float* __restrict__ W,
    const float* __restrict__ bias, float* __restrict__ dst0,
    float* __restrict__ dst1, float scale)
{
    __shared__ float As[16][64];
    __shared__ float Ws[16][68];
    int tid = threadIdx.x;
    int m0 = blockIdx.x * 64;
    int b = m0 / N_, n0 = m0 % N_;
    int o0 = blockIdx.y * 64;
    const float* Ab = A + (size_t)b * C_ * N_;
    float acc[4][4] = {};
    int la_k = tid >> 4;
    int la_m = (tid & 15) * 4;
    int lw_o = tid >> 2;
    int lw_k = (tid & 3) * 4;
    int u  = tid & 15;
    int v_ = tid >> 4;
    for (int kt = 0; kt < 16; ++kt) {
        int k0 = kt * 16;
        float4 av = *(const float4*)&Ab[(size_t)(k0 + la_k) * N_ + n0 + la_m];
        float4 wv = *(const float4*)&W[(size_t)(o0 + lw_o) * C_ + k0 + lw_k];
        __syncthreads();
        *(float4*)&As[la_k][la_m] = av;
        Ws[lw_k + 0][lw_o] = wv.x; Ws[lw_k + 1][lw_o] = wv.y;
        Ws[lw_k + 2][lw_o] = wv.z; Ws[lw_k + 3][lw_o] = wv.w;
        __syncthreads();
#pragma unroll
        for (int k = 0; k < 16; ++k) {
            float4 wf = *(const float4*)&Ws[k][u * 4];
            float a0 = As[k][v_], a1 = As[k][v_ + 16], a2 = As[k][v_ + 32], a3 = As[k][v_ + 48];
            acc[0][0] += wf.x * a0; acc[0][1] += wf.x * a1; acc[0][2] += wf.x * a2; acc[0][3] += wf.x * a3;
            acc[1][0] += wf.y * a0; acc[1][1] += wf.y * a1; acc[1][2] += wf.y * a2; acc[1][3] += wf.y * a3;
            acc[2][0] += wf.z * a0; acc[2][1] += wf.z * a1; acc[2][2] += wf.z * a2; acc[2][3] += wf.z * a3;
            acc[3][0] += wf.w * a0; acc[3][1] += wf.w * a1; acc[3][2] += wf.w * a2; acc[3][3] += wf.w * a3;
        }
    }
    int oc = o0 + u * 4;
    float b0v = bias[oc], b1v = bias[oc + 1], b2v = bias[oc + 2], b3v = bias[oc + 3];
    float* dst = dst0; int c2 = oc;
    if (dst1 && oc >= C_) { dst = dst1; c2 = oc - C_; }
    int h = c2 >> 5, d0 = c2 & 31;
    size_t base = ((size_t)b * NH_ + h) * N_ * D_;
#pragma unroll
    for (int j = 0; j < 4; ++j) {
        int n = n0 + v_ + j * 16;
        float4 val;
        val.x = (acc[0][j] + b0v) * scale;
        val.y = (acc[1][j] + b1v) * scale;
        val.z = (acc[2][j] + b2v) * scale;
        val.w = (acc[3][j] + b3v) * scale;
        *(float4*)&dst[base + (size_t)n * D_ + d0] = val;
    }
}

__global__ __launch_bounds__(256) void gemm_proj(
    const float* __restrict__ A, const float* __restrict__ W,
    const float* __restrict__ bias, float* __restrict__ out)
{
    __shared__ float As[16][64];
    __shared__ float Ws[16][68];
    int tid = threadIdx.x;
    int m0 = blockIdx.x * 64;
    int b = m0 / N_, n0 = m0 % N_;
    int o0 = blockIdx.y * 64;
    const float* Ab = A + (size_t)b * C_ * N_;
    float acc[4][4] = {};
    int la_k = tid >> 4;
    int la_m = (tid & 15) * 4;
    int lw_o = tid >> 2;
    int lw_k = (tid & 3) * 4;
    int u  = tid & 15;
    int v_ = tid >> 4;
    for (int kt = 0; kt < 16; ++kt) {
        int k0 = kt * 16;
        float4 av = *(const float4*)&Ab[(size_t)(k0 + la_k) * N_ + n0 + la_m];
        float4 wv = *(const float4*)&W[(size_t)(o0 + lw_o) * C_ + k0 + lw_k];
        __syncthreads();
        *(float4*)&As[la_k][la_m] = av;
        Ws[lw_k + 0][lw_o] = wv.x; Ws[lw_k + 1][lw_o] = wv.y;
        Ws[lw_k + 2][lw_o] = wv.z; Ws[lw_k + 3][lw_o] = wv.w;
        __syncthreads();
#pragma unroll
        for (int k = 0; k < 16; ++k) {
            float4 af = *(const float4*)&As[k][u * 4];
            float w0 = Ws[k][v_], w1 = Ws[k][v_ + 16], w2 = Ws[k][v_ + 32], w3 = Ws[k][v_ + 48];
            acc[0][0] += w0 * af.x; acc[0][1] += w0 * af.y; acc[0][2] += w0 * af.z; acc[0][3] += w0 * af.w;
            acc[1][0] += w1 * af.x; acc[1][1] += w1 * af.y; acc[1][2] += w1 * af.z; acc[1][3] += w1 * af.w;
            acc[2][0] += w2 * af.x; acc[2][1] += w2 * af.y; acc[2][2] += w2 * af.z; acc[2][3] += w2 * af.w;
            acc[3][0] += w3 * af.x; acc[3][1] += w3 * af.y; acc[3][2] += w3 * af.z; acc[3][3] += w3 * af.w;
        }
    }
#pragma unroll
    for (int i = 0; i < 4; ++i) {
        int o = o0 + v_ + i * 16;
        float bb = bias[o];
        float4 val;
        val.x = acc[i][0] + bb; val.y = acc[i][1] + bb;
        val.z = acc[i][2] + bb; val.w = acc[i][3] + bb;
        *(float4*)&out[((size_t)b * C_ + o) * N_ + n0 + u * 4] = val;
    }
}

// ---------------- fused attention (1024 threads, 16 waves) ----------------
struct AttnMisc {
    float rowmax[8];
    unsigned prefU[16];  // accumulated radix prefix per problem (8 rows x 2 k's)
    int remK[16];        // remaining rank per problem
    float coef[16];
    float pp[2];
    float wred[256];     // 16 waves x 16 slots
};

__global__ __launch_bounds__(1024, 4) void attn_kernel(
    const float* __restrict__ qh, const float* __restrict__ kh, const float* __restrict__ vh,
    const float* __restrict__ p1p, const float* __restrict__ p2p,
    float* __restrict__ aoT)
{
    extern __shared__ char smem[];
    float*    S  = (float*)smem;                       // 8*3140 fp32   (100480 B)
    float*    qs = (float*)(smem + 100480);            // 256 fp32      (1024 B)
    unsigned* hA = (unsigned*)(smem + 101504);         // 16*260 u32    (16640 B)
    unsigned* hB = (unsigned*)(smem + 118144);         // 16*260 u32    (16640 B)
    AttnMisc* M  = (AttnMisc*)(smem + 134784);

    int tid = threadIdx.x, lane = tid & 63, wid = tid >> 6;
    int bh = blockIdx.y, n0 = blockIdx.x * 8;
    size_t bhN = (size_t)bh * N_;

    if (tid < 256) qs[tid] = qh[(bhN + n0) * D_ + tid];
    if (tid < 16) { M->prefU[tid] = 0u; M->remK[tid] = (tid & 1) ? K2CNT : K1CNT; }
    if (tid == 0) { M->pp[0] = p1p[0]; M->pp[1] = p2p[0]; }
    for (int i = tid; i < 16 * HSTR; i += 1024) hA[i] = 0u;
    __syncthreads();

    // ---- scores + fused L1 histogram (key bits 31:24, one hist row per q-row)
    float lmax[8];
#pragma unroll
    for (int r = 0; r < 8; ++r) lmax[r] = -3.4e38f;
    for (int i = 0; i < 4; ++i) {
        int j = tid + (i << 10);
        if (j < N_) {
            const float4* kp = (const float4*)(kh + (bhN + j) * D_);
            float4 k4[8];
#pragma unroll
            for (int q = 0; q < 8; ++q) k4[q] = kp[q];
#pragma unroll
            for (int r = 0; r < 8; ++r) {
                float sacc = 0.f;
#pragma unroll
                for (int q = 0; q < 8; ++q) {
                    float4 q4 = *(const float4*)&qs[r * D_ + q * 4];
                    sacc += q4.x * k4[q].x + q4.y * k4[q].y + q4.z * k4[q].z + q4.w * k4[q].w;
                }
                S[r * SROW + j] = sacc;
                lmax[r] = fmaxf(lmax[r], sacc);
                atomicAdd(&hA[r * HSTR + (ordf(sacc) >> 24)], 1u);
            }
        }
    }
#pragma unroll
    for (int r = 0; r < 8; ++r) {
        float v = lmax[r];
#pragma unroll
        for (int d = 32; d; d >>= 1) v = fmaxf(v, __shfl_down(v, d, 64));
        if (lane == 0) M->wred[wid * 16 + r] = v;
    }
    __syncthreads();

    // ---- 4-level 8-bit radix select: 16 problems in parallel (wave w = prob w)
    for (int lvl = 0; lvl < 4; ++lvl) {
        if (lvl > 0) {
            int shift = 24 - 8 * lvl;
            unsigned pf[16];
#pragma unroll
            for (int p = 0; p < 16; ++p) pf[p] = M->prefU[p];
            unsigned* hcur = (lvl & 1) ? hB : hA;
            for (int i = 0; i < 4; ++i) {
                int j = tid + (i << 10);
                if (j < N_) {
#pragma unroll
                    for (int r = 0; r < 8; ++r) {
                        unsigned u = ordf(S[r * SROW + j]);
                        unsigned hi = u >> (shift + 8);
                        unsigned bin = (u >> shift) & 0xFFu;
                        if (hi == pf[r * 2])     atomicAdd(&hcur[(r * 2) * HSTR + bin], 1u);
                        if (hi == pf[r * 2 + 1]) atomicAdd(&hcur[(r * 2 + 1) * HSTR + bin], 1u);
                    }
                }
            }
            __syncthreads();
        }
        {   // search (16 waves, one problem each) + zero the other hist buffer
            unsigned* hcur = (lvl & 1) ? hB : hA;
            unsigned* hoth = (lvl & 1) ? hA : hB;
            if (lvl < 3)
                for (int i = tid; i < 16 * HSTR; i += 1024) hoth[i] = 0u;
            if (lvl == 0 && tid < 8) {
                float mm = -3.4e38f;
                for (int w = 0; w < 16; ++w) mm = fmaxf(mm, M->wred[w * 16 + tid]);
                M->rowmax[tid] = mm;
            }
            int prob = wid;
            const unsigned* hh = hcur + ((lvl == 0) ? (prob >> 1) * HSTR : prob * HSTR);
            int k = M->remK[prob];
            int h0 = (int)hh[lane * 4], h1 = (int)hh[lane * 4 + 1],
                h2 = (int)hh[lane * 4 + 2], h3 = (int)hh[lane * 4 + 3];
            int ls3 = h3, ls2 = ls3 + h2, ls1 = ls2 + h1, ls0 = ls1 + h0;
            int s = ls0;
#pragma unroll
            for (int d = 1; d < 64; d <<= 1) {
                int o = __shfl_down(s, d, 64);
                if (lane + d < 64) s += o;
            }
            int after = s - ls0;     // elements in bins above this lane's 4 bins
            int G0 = ls0 + after, G1 = ls1 + after, G2 = ls2 + after, G3 = ls3 + after;
            int selb = -1, selr = 0;
            if (G0 >= k && G0 - h0 < k) { selb = lane * 4;     selr = k - (G0 - h0); }
            if (G1 >= k && G1 - h1 < k) { selb = lane * 4 + 1; selr = k - (G1 - h1); }
            if (G2 >= k && G2 - h2 < k) { selb = lane * 4 + 2; selr = k - (G2 - h2); }
            if (G3 >= k && G3 - h3 < k) { selb = lane * 4 + 3; selr = k - (G3 - h3); }
            if (selb >= 0) {
                M->prefU[prob] = (M->prefU[prob] << 8) | (unsigned)selb;
                M->remK[prob] = selr;
            }
        }
        __syncthreads();
    }

    // ---- masked exp sums + signed markers written in place ----
    unsigned t1r[8], t2r[8]; float rm[8];
#pragma unroll
    for (int r = 0; r < 8; ++r) {
        t1r[r] = M->prefU[r * 2];
        t2r[r] = M->prefU[r * 2 + 1];
        rm[r] = M->rowmax[r];
    }
    float ls1a[8] = {}, ls2a[8] = {};
    for (int i = 0; i < 4; ++i) {
        int j = tid + (i << 10);
        if (j < N_) {
#pragma unroll
            for (int r = 0; r < 8; ++r) {
                float a = S[r * SROW + j];
                unsigned u = ordf(a);
                float outv = 0.f;
                if (u >= t1r[r]) {
                    float w = __expf(a - rm[r]);
                    ls1a[r] += w;
                    if (u >= t2r[r]) { ls2a[r] += w; outv = w; }
                    else outv = -w;
                }
                S[r * SROW + j] = outv;
            }
        }
    }
#pragma unroll
    for (int r = 0; r < 8; ++r) {
        float a1 = ls1a[r], a2 = ls2a[r];
#pragma unroll
        for (int d = 32; d; d >>= 1) { a1 += __shfl_down(a1, d, 64); a2 += __shfl_down(a2, d, 64); }
        if (lane == 0) { M->wred[wid * 16 + r * 2] = a1; M->wred[wid * 16 + r * 2 + 1] = a2; }
    }
    // preload V tile 0 into vt0 (= hA, free after selection)
    float* vt0 = (float*)hA;
    float* vt1 = (float*)hB;
    *(float4*)&vt0[tid * 4] = *(const float4*)&vh[bhN * D_ + tid * 4];
    __syncthreads();
    if (tid < 16) {
        float ssum = 0.f;
        for (int w = 0; w < 16; ++w) ssum += M->wred[w * 16 + tid];
        M->coef[tid] = ((tid & 1) ? M->pp[1] : M->pp[0]) / ssum;
    }
    __syncthreads();

    // ---- AV with double-buffered V tiles, coeff transform fused at read ----
    int r_ = lane >> 3, dq = lane & 7;
    float c1 = M->coef[r_ * 2];
    float c12 = c1 + M->coef[r_ * 2 + 1];
    float acc0 = 0.f, acc1 = 0.f, acc2 = 0.f, acc3 = 0.f;
    const int NT = (N_ + TJ - 1) / TJ;   // 25
    for (int t = 0; t < NT; ++t) {
        float* cur = (t & 1) ? vt1 : vt0;
        float* nxt = (t & 1) ? vt0 : vt1;
        int j0 = t * TJ;
        int cnt = min(TJ, N_ - j0);
        float4 pfv; bool havepf = false;
        int j0n = j0 + TJ;
        if (j0n < N_) {
            int cnt2 = min(TJ, N_ - j0n);
            if (tid < cnt2 * 8) {
                pfv = *(const float4*)&vh[(bhN + j0n) * D_ + tid * 4];
                havepf = true;
            }
        }
        int lim = min(8, cnt - wid * 8);
        const float* Sr = S + r_ * SROW + j0 + wid * 8;
        const float* vb = cur + (wid * 8) * D_ + dq * 4;
        for (int jj = 0; jj < lim; ++jj) {
            float v = Sr[jj];
            float c = (v > 0.f) ? v * c12 : (-v) * c1;
            float4 v4 = *(const float4*)&vb[jj * D_];
            acc0 += c * v4.x; acc1 += c * v4.y; acc2 += c * v4.z; acc3 += c * v4.w;
        }
        if (havepf) *(float4*)&nxt[tid * 4] = pfv;
        __syncthreads();
    }
    float* red = vt1;   // t=24 (even) computed from vt0; vt1 is dead
    *(float4*)&red[(wid << 8) + (lane << 2)] = make_float4(acc0, acc1, acc2, acc3);
    __syncthreads();
    if (tid < 256) {
        float o = 0.f;
        for (int w = 0; w < 16; ++w) o += red[(w << 8) + tid];
        int r = tid >> 5, d = tid & 31;
        int b = bh >> 3, h = bh & 7;
        aoT[((size_t)(b * C_ + h * 32 + d)) * N_ + n0 + r] = o;
    }
}

static const int ATTN_SMEM = 134784 + (int)sizeof(AttnMisc);

extern "C" void kernel_launch(void* const* d_in, const int* in_sizes, int n_in,
                              void* d_out, int out_size, void* d_ws, size_t ws_size,
                              hipStream_t stream)
{
    (void)in_sizes; (void)n_in; (void)out_size; (void)ws_size;
    const float* x    = (const float*)d_in[0];
    const float* y    = (const float*)d_in[1];
    const float* q_w  = (const float*)d_in[2];
    const float* q_b  = (const float*)d_in[3];
    const float* kv_w = (const float*)d_in[4];
    const float* kv_b = (const float*)d_in[5];
    const float* p_w  = (const float*)d_in[6];
    const float* p_b  = (const float*)d_in[7];
    const float* lnw  = (const float*)d_in[8];
    const float* lnb  = (const float*)d_in[9];
    const float* a1p  = (const float*)d_in[10];
    const float* a2p  = (const float*)d_in[11];
    float* out = (float*)d_out;

    float* ws = (float*)d_ws;
    const size_t PLANE = (size_t)B_ * C_ * N_;
    float* yp  = ws;
    float* yfT = ws + PLANE;
    float* qh_ = ws + 2 * PLANE;
    float* kh_ = ws + 3 * PLANE;
    float* vh_ = ws + 4 * PLANE;
    float* aoT = ws + 5 * PLANE;

    pool_kernel<<<dim3((unsigned)(PLANE / 256)), 256, 0, stream>>>(y, yp);
    ln_kernel<<<dim3(B_ * N_), 256, 0, stream>>>(yp, lnw, lnb, yfT);
    gemm_qkv<<<dim3(98, 4), 256, 0, stream>>>(x, q_w, q_b, qh_, nullptr, 0.17677669529663687f);
    gemm_qkv<<<dim3(98, 8), 256, 0, stream>>>(yfT, kv_w, kv_b, kh_, vh_, 1.0f);
    hipFuncSetAttribute(reinterpret_cast<const void*>(attn_kernel),
                        hipFuncAttributeMaxDynamicSharedMemorySize, ATTN_SMEM);
    attn_kernel<<<dim3(N_ / 8, B_ * NH_), 1024, ATTN_SMEM, stream>>>(qh_, kh_, vh_, a1p, a2p, aoT);
    gemm_proj<<<dim3(98, 4), 256, 0, stream>>>(aoT, p_w, p_b, out);
}